// Round 1
// baseline (2419.632 us; speedup 1.0000x reference)
//
#include <hip/hip_runtime.h>
#include <cstdint>
#include <cstddef>

// Problem constants (match reference setup_inputs)
#define NPTS 16384   // N
#define NSAMP 1024   // SAMPLES
#define KNBR 32      // MAX_NEIGHBORS
#define NCH 128      // C
#define TPB 1024     // FPS block size
#define PPT (NPTS / TPB)  // points per thread in FPS = 16

// ---------------------------------------------------------------------------
// Kernel 1: farthest point sampling. One block per batch. Sequential over
// S-1 iterations; per iteration, block-wide argmax of running min-distance.
// Arithmetic must match numpy fp32 exactly: no FMA contraction, sum order
// (dx*dx + dy*dy) + dz*dz, first-index tie-break on argmax.
// ---------------------------------------------------------------------------
__global__ __launch_bounds__(TPB) void fps_kernel(
    const float* __restrict__ xyz, float* __restrict__ centroids) {
#pragma clang fp contract(off)
  const int b = blockIdx.x;
  const int t = threadIdx.x;
  const float* px = xyz + (size_t)b * NPTS * 3;

  float x[PPT], y[PPT], z[PPT], md[PPT];
#pragma unroll
  for (int j = 0; j < PPT; ++j) {
    const int p = j * TPB + t;
    x[j] = px[p * 3 + 0];
    y[j] = px[p * 3 + 1];
    z[j] = px[p * 3 + 2];
    md[j] = 1e10f;
  }

  __shared__ float s_last[3];
  __shared__ float s_wval[16];
  __shared__ int s_widx[16];

  if (t == 0) {
    const float cx = px[0], cy = px[1], cz = px[2];
    s_last[0] = cx; s_last[1] = cy; s_last[2] = cz;
    float* co = centroids + (size_t)b * NSAMP * 3;
    co[0] = cx; co[1] = cy; co[2] = cz;
  }
  __syncthreads();

  for (int s = 1; s < NSAMP; ++s) {
    const float lx = s_last[0];
    const float ly = s_last[1];
    const float lz = s_last[2];
    float bv = -1.0f;
    int bi = 0;
#pragma unroll
    for (int j = 0; j < PPT; ++j) {
      const float dx = x[j] - lx;
      const float dy = y[j] - ly;
      const float dz = z[j] - lz;
      const float d = (dx * dx + dy * dy) + dz * dz;  // contract(off): no FMA
      const float m = fminf(md[j], d);
      md[j] = m;
      // strict > keeps earliest p on exact ties (p ascending in j)
      if (m > bv) { bv = m; bi = j * TPB + t; }
    }
    // wave-level argmax: max value; on exact tie, smaller index (numpy argmax)
#pragma unroll
    for (int off = 32; off > 0; off >>= 1) {
      const float ov = __shfl_xor(bv, off);
      const int oi = __shfl_xor(bi, off);
      if (ov > bv || (ov == bv && oi < bi)) { bv = ov; bi = oi; }
    }
    if ((t & 63) == 0) { s_wval[t >> 6] = bv; s_widx[t >> 6] = bi; }
    __syncthreads();
    if (t < 64) {
      // wave 0 reduces the 16 per-wave winners (lanes 0..15 hold data;
      // xor masks < 16 keep the reduction within the group)
      float v = (t < 16) ? s_wval[t] : -1.0f;
      int i = (t < 16) ? s_widx[t] : 0x7fffffff;
#pragma unroll
      for (int off = 8; off > 0; off >>= 1) {
        const float ov = __shfl_xor(v, off);
        const int oi = __shfl_xor(i, off);
        if (ov > v || (ov == v && oi < i)) { v = ov; i = oi; }
      }
      if (t == 0) {
        const float* q = px + (size_t)i * 3;  // L2-hot (xyz = 192 KB/batch)
        const float cx = q[0], cy = q[1], cz = q[2];
        s_last[0] = cx; s_last[1] = cy; s_last[2] = cz;
        float* co = centroids + ((size_t)b * NSAMP + s) * 3;
        co[0] = cx; co[1] = cy; co[2] = cz;
      }
    }
    __syncthreads();
  }
}

// ---------------------------------------------------------------------------
// Kernel 2: ball query (first K in-radius by index order, pad with first hit)
// + gather. One wave per (b,s) centroid; 4 waves per 256-thread block.
// Ordered chunk scan with ballot + prefix popcount, early exit at K found.
// ---------------------------------------------------------------------------
__global__ __launch_bounds__(256) void group_kernel(
    const float* __restrict__ xyz, const float* __restrict__ feat,
    const float* __restrict__ centroids,
    float* __restrict__ gxyz, float* __restrict__ gfeat) {
#pragma clang fp contract(off)
  const int wave = threadIdx.x >> 6;
  const int lane = threadIdx.x & 63;
  const int gw = blockIdx.x * 4 + wave;  // == b * NSAMP + s
  const int b = gw >> 10;

  const float* px = xyz + (size_t)b * NPTS * 3;
  const float* pc = centroids + (size_t)gw * 3;
  const float cx = pc[0], cy = pc[1], cz = pc[2];
  // float32(0.04): numpy compares f32 sqd against python-double 0.04 demoted
  // to f32. NOT 0.2f*0.2f (that's a different float, 1 ulp larger).
  const float rr = 0.04f;

  __shared__ int sh_idx[4][KNBR];
  __shared__ float sh_gx[4][KNBR * 3];

  int cnt = 0;
  for (int n0 = 0; n0 < NPTS && cnt < KNBR; n0 += 64) {
    const int p = n0 + lane;
    const float xx = px[p * 3 + 0];
    const float yy = px[p * 3 + 1];
    const float zz = px[p * 3 + 2];
    const float dx = xx - cx;
    const float dy = yy - cy;
    const float dz = zz - cz;
    const float d = (dx * dx + dy * dy) + dz * dz;  // contract(off): no FMA
    const bool in = d <= rr;
    const unsigned long long mask = __ballot(in);
    const int pos = cnt + (int)__popcll(mask & ((1ull << lane) - 1ull));
    if (in && pos < KNBR) {
      sh_idx[wave][pos] = p;
      sh_gx[wave][pos * 3 + 0] = dx;
      sh_gx[wave][pos * 3 + 1] = dy;
      sh_gx[wave][pos * 3 + 2] = dz;
    }
    cnt += (int)__popcll(mask);
  }
  // Safety: cannot happen (centroid is itself in-ball), but avoid garbage
  // indices if it somehow does.
  if (cnt == 0 && lane == 0) {
    sh_idx[wave][0] = 0;
    sh_gx[wave][0] = px[0] - cx;
    sh_gx[wave][1] = px[1] - cy;
    sh_gx[wave][2] = px[2] - cz;
  }
  const int nf0 = (cnt < 1) ? 1 : cnt;
  const int nf = (nf0 < KNBR) ? nf0 : KNBR;
  __syncthreads();
  // pad slots [nf, K) with the first hit (matches reference padding)
  if (lane < KNBR && lane >= nf) {
    sh_idx[wave][lane] = sh_idx[wave][0];
    sh_gx[wave][lane * 3 + 0] = sh_gx[wave][0];
    sh_gx[wave][lane * 3 + 1] = sh_gx[wave][1];
    sh_gx[wave][lane * 3 + 2] = sh_gx[wave][2];
  }
  __syncthreads();

  // write grouped_xyz: 96 floats per centroid
  float* ox = gxyz + (size_t)gw * KNBR * 3;
  const float* shf = sh_gx[wave];
  for (int j = lane; j < KNBR * 3; j += 64) ox[j] = shf[j];

  // gather features: K rows of 128 floats, float2 per lane (512 B/row)
  float* og = gfeat + (size_t)gw * KNBR * NCH;
  const float* pf = feat + (size_t)b * NPTS * NCH;
#pragma unroll 4
  for (int k = 0; k < KNBR; ++k) {
    const int row = sh_idx[wave][k];
    const float2 v = ((const float2*)(pf + (size_t)row * NCH))[lane];
    ((float2*)(og + (size_t)k * NCH))[lane] = v;
  }
}

extern "C" void kernel_launch(void* const* d_in, const int* in_sizes, int n_in,
                              void* d_out, int out_size, void* d_ws, size_t ws_size,
                              hipStream_t stream) {
  const float* xyz = (const float*)d_in[0];
  const float* feat = (const float*)d_in[1];
  float* out = (float*)d_out;
  const int B = in_sizes[0] / (NPTS * 3);

  float* centroids = out;                                   // [B,S,3]
  float* gxyz = centroids + (size_t)B * NSAMP * 3;          // [B,S,K,3]
  float* gfeat = gxyz + (size_t)B * NSAMP * KNBR * 3;       // [B,S,K,C]

  fps_kernel<<<B, TPB, 0, stream>>>(xyz, centroids);
  group_kernel<<<(B * NSAMP) / 4, 256, 0, stream>>>(xyz, feat, centroids, gxyz, gfeat);
}

// Round 2
// 1970.027 us; speedup vs baseline: 1.2282x; 1.2282x over previous
//
#include <hip/hip_runtime.h>
#include <cstdint>
#include <cstddef>

// Problem constants (match reference setup_inputs)
#define NPTS 16384   // N
#define NSAMP 1024   // SAMPLES
#define KNBR 32      // MAX_NEIGHBORS
#define NCH 128      // C
#define FPS_TPB 512              // FPS block size (8 waves, 2/SIMD)
#define FPS_PPT (NPTS / FPS_TPB) // points per thread = 32

// ---------------------------------------------------------------------------
// Kernel 1: farthest point sampling. One block per batch (4 blocks total).
// Per iteration: per-thread min-dist update over 32 register-resident points,
// wave butterfly argmax on a packed u64 key, ONE barrier, replicated 8-way
// cross-wave reduce from double-buffered LDS.
//
// Exactness contract (absmax must stay ~0): distance = (dx*dx+dy*dy)+dz*dz
// with contract(off) (no FMA), md = fminf(md, d), argmax tie-break = smallest
// original index. Thread-local scan: strict > keeps smallest j (p = j*TPB+t
// ascending in j). Cross-lane: key = (f32bits(val)<<32) | ~idx, max-reduce —
// min-dists are >= 0 so the f32 bit pattern is monotone as u32; ~idx makes
// larger key == smaller index on exact value ties.
//
// __launch_bounds__(512, 2): 2 waves/EU -> 256-VGPR cap. The 128 array
// floats MUST stay in registers (round-0's 1024-thread/128-cap version
// spilled: VGPR_Count=60, ~26 instr/pt instead of ~12).
// ---------------------------------------------------------------------------
__global__ __launch_bounds__(FPS_TPB, 2) void fps_kernel(
    const float* __restrict__ xyz, float* __restrict__ centroids) {
#pragma clang fp contract(off)
  const int b = blockIdx.x;
  const int t = threadIdx.x;
  const float* px = xyz + (size_t)b * NPTS * 3;

  float x[FPS_PPT], y[FPS_PPT], z[FPS_PPT], md[FPS_PPT];
#pragma unroll
  for (int j = 0; j < FPS_PPT; ++j) {
    const int p = j * FPS_TPB + t;
    x[j] = px[p * 3 + 0];
    y[j] = px[p * 3 + 1];
    z[j] = px[p * 3 + 2];
    md[j] = 1e10f;
  }

  __shared__ unsigned long long s_wkey[2][FPS_TPB / 64];  // double-buffered

  float* co = centroids + (size_t)b * NSAMP * 3;
  if (t == 0) { co[0] = px[0]; co[1] = px[1]; co[2] = px[2]; }

  unsigned int widx = 0;  // winner of previous iteration (uniform)

  for (int s = 1; s < NSAMP; ++s) {
    // Broadcast load of last centroid's coords (uniform address -> scalar
    // load; xyz is read-only so the scalar cache is safe; L1/L2-hot).
    const int wi = __builtin_amdgcn_readfirstlane((int)widx);
    const float lx = px[wi * 3 + 0];
    const float ly = px[wi * 3 + 1];
    const float lz = px[wi * 3 + 2];

    float bv = -1.0f;
    int bj = 0;
#pragma unroll
    for (int j = 0; j < FPS_PPT; ++j) {
      const float dx = x[j] - lx;
      const float dy = y[j] - ly;
      const float dz = z[j] - lz;
      const float d = (dx * dx + dy * dy) + dz * dz;  // contract(off): no FMA
      const float m = fminf(md[j], d);
      md[j] = m;
      if (m > bv) { bv = m; bj = j; }  // strict >: keeps smallest j on ties
    }
    const unsigned int bi = (unsigned int)(bj * FPS_TPB + t);
    unsigned long long key =
        ((unsigned long long)__float_as_uint(bv) << 32) | (unsigned int)(~bi);

    // intra-wave butterfly max (6 steps over 64 lanes)
#pragma unroll
    for (int off = 1; off < 64; off <<= 1) {
      const unsigned long long ok = __shfl_xor(key, off);
      if (ok > key) key = ok;
    }
    if ((t & 63) == 0) s_wkey[s & 1][t >> 6] = key;
    __syncthreads();  // the ONLY barrier per iteration (LDS double-buffered)

    // replicated cross-wave reduce: all threads read the 8 wave winners
    // (same-address LDS reads broadcast, no conflicts)
    unsigned long long best = s_wkey[s & 1][0];
#pragma unroll
    for (int w = 1; w < FPS_TPB / 64; ++w) {
      const unsigned long long k2 = s_wkey[s & 1][w];
      if (k2 > best) best = k2;
    }
    widx = ~(unsigned int)best;

    if (t == 0) {
      const float* q = px + (size_t)widx * 3;  // warms L1 for next iter's
      co[s * 3 + 0] = q[0];                    // broadcast load too
      co[s * 3 + 1] = q[1];
      co[s * 3 + 2] = q[2];
    }
  }
}

// ---------------------------------------------------------------------------
// Kernel 2: ball query (first K in-radius by index order, pad with first hit)
// + gather. One wave per (b,s) centroid; 4 waves per 256-thread block.
// Ordered chunk scan with ballot + prefix popcount, early exit at K found.
// (Validated bit-exact in round 0; unchanged.)
// ---------------------------------------------------------------------------
__global__ __launch_bounds__(256) void group_kernel(
    const float* __restrict__ xyz, const float* __restrict__ feat,
    const float* __restrict__ centroids,
    float* __restrict__ gxyz, float* __restrict__ gfeat) {
#pragma clang fp contract(off)
  const int wave = threadIdx.x >> 6;
  const int lane = threadIdx.x & 63;
  const int gw = blockIdx.x * 4 + wave;  // == b * NSAMP + s
  const int b = gw >> 10;

  const float* px = xyz + (size_t)b * NPTS * 3;
  const float* pc = centroids + (size_t)gw * 3;
  const float cx = pc[0], cy = pc[1], cz = pc[2];
  // float32(0.04): numpy compares f32 sqd against python-double 0.04 demoted
  // to f32. NOT 0.2f*0.2f (that's a different float, 1 ulp larger).
  const float rr = 0.04f;

  __shared__ int sh_idx[4][KNBR];
  __shared__ float sh_gx[4][KNBR * 3];

  int cnt = 0;
  for (int n0 = 0; n0 < NPTS && cnt < KNBR; n0 += 64) {
    const int p = n0 + lane;
    const float xx = px[p * 3 + 0];
    const float yy = px[p * 3 + 1];
    const float zz = px[p * 3 + 2];
    const float dx = xx - cx;
    const float dy = yy - cy;
    const float dz = zz - cz;
    const float d = (dx * dx + dy * dy) + dz * dz;  // contract(off): no FMA
    const bool in = d <= rr;
    const unsigned long long mask = __ballot(in);
    const int pos = cnt + (int)__popcll(mask & ((1ull << lane) - 1ull));
    if (in && pos < KNBR) {
      sh_idx[wave][pos] = p;
      sh_gx[wave][pos * 3 + 0] = dx;
      sh_gx[wave][pos * 3 + 1] = dy;
      sh_gx[wave][pos * 3 + 2] = dz;
    }
    cnt += (int)__popcll(mask);
  }
  // Safety: cannot happen (centroid is itself in-ball), but avoid garbage
  // indices if it somehow does.
  if (cnt == 0 && lane == 0) {
    sh_idx[wave][0] = 0;
    sh_gx[wave][0] = px[0] - cx;
    sh_gx[wave][1] = px[1] - cy;
    sh_gx[wave][2] = px[2] - cz;
  }
  const int nf0 = (cnt < 1) ? 1 : cnt;
  const int nf = (nf0 < KNBR) ? nf0 : KNBR;
  __syncthreads();
  // pad slots [nf, K) with the first hit (matches reference padding)
  if (lane < KNBR && lane >= nf) {
    sh_idx[wave][lane] = sh_idx[wave][0];
    sh_gx[wave][lane * 3 + 0] = sh_gx[wave][0];
    sh_gx[wave][lane * 3 + 1] = sh_gx[wave][1];
    sh_gx[wave][lane * 3 + 2] = sh_gx[wave][2];
  }
  __syncthreads();

  // write grouped_xyz: 96 floats per centroid
  float* ox = gxyz + (size_t)gw * KNBR * 3;
  const float* shf = sh_gx[wave];
  for (int j = lane; j < KNBR * 3; j += 64) ox[j] = shf[j];

  // gather features: K rows of 128 floats, float2 per lane (512 B/row)
  float* og = gfeat + (size_t)gw * KNBR * NCH;
  const float* pf = feat + (size_t)b * NPTS * NCH;
#pragma unroll 4
  for (int k = 0; k < KNBR; ++k) {
    const int row = sh_idx[wave][k];
    const float2 v = ((const float2*)(pf + (size_t)row * NCH))[lane];
    ((float2*)(og + (size_t)k * NCH))[lane] = v;
  }
}

extern "C" void kernel_launch(void* const* d_in, const int* in_sizes, int n_in,
                              void* d_out, int out_size, void* d_ws, size_t ws_size,
                              hipStream_t stream) {
  const float* xyz = (const float*)d_in[0];
  const float* feat = (const float*)d_in[1];
  float* out = (float*)d_out;
  const int B = in_sizes[0] / (NPTS * 3);

  float* centroids = out;                                   // [B,S,3]
  float* gxyz = centroids + (size_t)B * NSAMP * 3;          // [B,S,K,3]
  float* gfeat = gxyz + (size_t)B * NSAMP * KNBR * 3;       // [B,S,K,C]

  fps_kernel<<<B, FPS_TPB, 0, stream>>>(xyz, centroids);
  group_kernel<<<(B * NSAMP) / 4, 256, 0, stream>>>(xyz, feat, centroids, gxyz, gfeat);
}

// Round 3
// 1959.247 us; speedup vs baseline: 1.2350x; 1.0055x over previous
//
#include <hip/hip_runtime.h>
#include <cstdint>
#include <cstddef>

// Problem constants (match reference setup_inputs)
#define NPTS 16384   // N
#define NSAMP 1024   // SAMPLES
#define KNBR 32      // MAX_NEIGHBORS
#define NCH 128      // C
#define FPS_TPB 512              // FPS block size (8 waves, 2/SIMD)
#define FPS_PPT (NPTS / FPS_TPB) // points per thread = 32

// ---------------------------------------------------------------------------
// Kernel 1: farthest point sampling. One block per batch (4 blocks total).
//
// ROUND-2 LESSON (VGPR_Count=88): loop-indexed per-thread arrays are NOT
// promoted to VGPRs by the AMDGPU backend above its promote-alloca size
// threshold, even with a 256-reg budget — they live in scratch and the
// kernel eats ~96 scratch loads/thread/iteration. Fix: macro-expanded NAMED
// scalars (SSA values, cannot be demoted). Expansion order 0..31 ascending
// preserves the smallest-index tie-break of the thread-local argmax scan.
//
// Exactness contract (absmax must stay 0): d = (dx*dx+dy*dy)+dz*dz with
// contract(off) (no FMA), md = fminf(md, d), argmax tie-break = smallest
// original index (thread-local: strict >, ascending i; cross-lane: packed
// key (f32bits(val)<<32)|~idx max-reduced — min-dists >= 0 so f32 bits are
// monotone as u32; ~idx makes larger key == smaller index on value ties).
// ---------------------------------------------------------------------------

#define PT_FOREACH(X) \
  X(0) X(1) X(2) X(3) X(4) X(5) X(6) X(7) \
  X(8) X(9) X(10) X(11) X(12) X(13) X(14) X(15) \
  X(16) X(17) X(18) X(19) X(20) X(21) X(22) X(23) \
  X(24) X(25) X(26) X(27) X(28) X(29) X(30) X(31)

__global__ __launch_bounds__(FPS_TPB, 2) void fps_kernel(
    const float* __restrict__ xyz, float* __restrict__ centroids) {
#pragma clang fp contract(off)
  const int b = blockIdx.x;
  const int t = threadIdx.x;
  const float* px = xyz + (size_t)b * NPTS * 3;

#define DECL_PT(i) float x##i, y##i, z##i, m##i;
  PT_FOREACH(DECL_PT)
#undef DECL_PT

#define LOAD_PT(i)                              \
  {                                             \
    const int p = (i) * FPS_TPB + t;            \
    x##i = px[p * 3 + 0];                       \
    y##i = px[p * 3 + 1];                       \
    z##i = px[p * 3 + 2];                       \
    m##i = 1e10f;                               \
  }
  PT_FOREACH(LOAD_PT)
#undef LOAD_PT

  __shared__ unsigned long long s_wkey[2][FPS_TPB / 64];  // double-buffered

  float* co = centroids + (size_t)b * NSAMP * 3;

  // current "last centroid" coords, kept in registers across iterations
  float lx = px[0], ly = px[1], lz = px[2];
  if (t == 0) { co[0] = lx; co[1] = ly; co[2] = lz; }

  for (int s = 1; s < NSAMP; ++s) {
    float bv = -1.0f;
    int bj = 0;
#define UPD_PT(i)                                                   \
    {                                                               \
      const float dx = x##i - lx;                                   \
      const float dy = y##i - ly;                                   \
      const float dz = z##i - lz;                                   \
      const float d = (dx * dx + dy * dy) + dz * dz; /* no FMA */   \
      const float mm = fminf(m##i, d);                              \
      m##i = mm;                                                    \
      if (mm > bv) { bv = mm; bj = (i); }  /* strict >: min index */\
    }
    PT_FOREACH(UPD_PT)
#undef UPD_PT

    const unsigned int bi = (unsigned int)(bj * FPS_TPB + t);
    unsigned long long key =
        ((unsigned long long)__float_as_uint(bv) << 32) | (unsigned int)(~bi);

    // intra-wave butterfly max (6 steps over 64 lanes)
#pragma unroll
    for (int off = 1; off < 64; off <<= 1) {
      const unsigned long long ok = __shfl_xor(key, off);
      if (ok > key) key = ok;
    }
    if ((t & 63) == 0) s_wkey[s & 1][t >> 6] = key;
    __syncthreads();  // the ONLY barrier per iteration (LDS double-buffered)

    // replicated cross-wave reduce: all threads read the 8 wave winners
    // (same-address LDS reads broadcast, no conflicts)
    unsigned long long best = s_wkey[s & 1][0];
#pragma unroll
    for (int w = 1; w < FPS_TPB / 64; ++w) {
      const unsigned long long k2 = s_wkey[s & 1][w];
      if (k2 > best) best = k2;
    }
    const unsigned int widx = ~(unsigned int)best;

    // winner coords: all lanes load the same address -> one broadcast
    // vector transaction (no readfirstlane: keep it a VMEM load, L2-hot)
    lx = px[widx * 3 + 0];
    ly = px[widx * 3 + 1];
    lz = px[widx * 3 + 2];
    if (t == 0) {
      co[s * 3 + 0] = lx;
      co[s * 3 + 1] = ly;
      co[s * 3 + 2] = lz;
    }
  }
}

// ---------------------------------------------------------------------------
// Kernel 2: ball query (first K in-radius by index order, pad with first hit)
// + gather. One wave per (b,s) centroid; 4 waves per 256-thread block.
// Ordered chunk scan with ballot + prefix popcount, early exit at K found.
// (Validated bit-exact in round 0; unchanged.)
// ---------------------------------------------------------------------------
__global__ __launch_bounds__(256) void group_kernel(
    const float* __restrict__ xyz, const float* __restrict__ feat,
    const float* __restrict__ centroids,
    float* __restrict__ gxyz, float* __restrict__ gfeat) {
#pragma clang fp contract(off)
  const int wave = threadIdx.x >> 6;
  const int lane = threadIdx.x & 63;
  const int gw = blockIdx.x * 4 + wave;  // == b * NSAMP + s
  const int b = gw >> 10;

  const float* px = xyz + (size_t)b * NPTS * 3;
  const float* pc = centroids + (size_t)gw * 3;
  const float cx = pc[0], cy = pc[1], cz = pc[2];
  // float32(0.04): numpy compares f32 sqd against python-double 0.04 demoted
  // to f32. NOT 0.2f*0.2f (that's a different float, 1 ulp larger).
  const float rr = 0.04f;

  __shared__ int sh_idx[4][KNBR];
  __shared__ float sh_gx[4][KNBR * 3];

  int cnt = 0;
  for (int n0 = 0; n0 < NPTS && cnt < KNBR; n0 += 64) {
    const int p = n0 + lane;
    const float xx = px[p * 3 + 0];
    const float yy = px[p * 3 + 1];
    const float zz = px[p * 3 + 2];
    const float dx = xx - cx;
    const float dy = yy - cy;
    const float dz = zz - cz;
    const float d = (dx * dx + dy * dy) + dz * dz;  // contract(off): no FMA
    const bool in = d <= rr;
    const unsigned long long mask = __ballot(in);
    const int pos = cnt + (int)__popcll(mask & ((1ull << lane) - 1ull));
    if (in && pos < KNBR) {
      sh_idx[wave][pos] = p;
      sh_gx[wave][pos * 3 + 0] = dx;
      sh_gx[wave][pos * 3 + 1] = dy;
      sh_gx[wave][pos * 3 + 2] = dz;
    }
    cnt += (int)__popcll(mask);
  }
  // Safety: cannot happen (centroid is itself in-ball), but avoid garbage
  // indices if it somehow does.
  if (cnt == 0 && lane == 0) {
    sh_idx[wave][0] = 0;
    sh_gx[wave][0] = px[0] - cx;
    sh_gx[wave][1] = px[1] - cy;
    sh_gx[wave][2] = px[2] - cz;
  }
  const int nf0 = (cnt < 1) ? 1 : cnt;
  const int nf = (nf0 < KNBR) ? nf0 : KNBR;
  __syncthreads();
  // pad slots [nf, K) with the first hit (matches reference padding)
  if (lane < KNBR && lane >= nf) {
    sh_idx[wave][lane] = sh_idx[wave][0];
    sh_gx[wave][lane * 3 + 0] = sh_gx[wave][0];
    sh_gx[wave][lane * 3 + 1] = sh_gx[wave][1];
    sh_gx[wave][lane * 3 + 2] = sh_gx[wave][2];
  }
  __syncthreads();

  // write grouped_xyz: 96 floats per centroid
  float* ox = gxyz + (size_t)gw * KNBR * 3;
  const float* shf = sh_gx[wave];
  for (int j = lane; j < KNBR * 3; j += 64) ox[j] = shf[j];

  // gather features: K rows of 128 floats, float2 per lane (512 B/row)
  float* og = gfeat + (size_t)gw * KNBR * NCH;
  const float* pf = feat + (size_t)b * NPTS * NCH;
#pragma unroll 4
  for (int k = 0; k < KNBR; ++k) {
    const int row = sh_idx[wave][k];
    const float2 v = ((const float2*)(pf + (size_t)row * NCH))[lane];
    ((float2*)(og + (size_t)k * NCH))[lane] = v;
  }
}

extern "C" void kernel_launch(void* const* d_in, const int* in_sizes, int n_in,
                              void* d_out, int out_size, void* d_ws, size_t ws_size,
                              hipStream_t stream) {
  const float* xyz = (const float*)d_in[0];
  const float* feat = (const float*)d_in[1];
  float* out = (float*)d_out;
  const int B = in_sizes[0] / (NPTS * 3);

  float* centroids = out;                                   // [B,S,3]
  float* gxyz = centroids + (size_t)B * NSAMP * 3;          // [B,S,K,3]
  float* gfeat = gxyz + (size_t)B * NSAMP * KNBR * 3;       // [B,S,K,C]

  fps_kernel<<<B, FPS_TPB, 0, stream>>>(xyz, centroids);
  group_kernel<<<(B * NSAMP) / 4, 256, 0, stream>>>(xyz, feat, centroids, gxyz, gfeat);
}

// Round 4
// 1929.110 us; speedup vs baseline: 1.2543x; 1.0156x over previous
//
#include <hip/hip_runtime.h>
#include <cstdint>
#include <cstddef>

// Problem constants (match reference setup_inputs)
#define NPTS 16384   // N
#define NSAMP 1024   // SAMPLES
#define KNBR 32      // MAX_NEIGHBORS
#define NCH 128      // C
#define FPS_TPB 512              // FPS block size (8 waves, 2/SIMD)
#define FPS_PPT (NPTS / FPS_TPB) // points per thread = 32

// ---------------------------------------------------------------------------
// Kernel 1: farthest point sampling. One block per batch (4 blocks total).
//
// ROUND-2 LESSON (VGPR_Count=88, arrays): promote-alloca won't put large
// loop-indexed arrays in VGPRs -> scratch.
// ROUND-3 LESSON (VGPR_Count=88, named scalars): __launch_bounds__(512,2)
// only sets the MINIMUM waves/EU. The scheduler still targets higher
// occupancy (5 waves/EU at 88 regs) by rematerializing the 96 loop-invariant
// coordinate loads from global EVERY iteration (~32 dwordx3/thread/iter).
// Fix: amdgpu_waves_per_eu(2,2) pins the occupancy target, giving the
// allocator a 256-VGPR budget and no incentive to shed pressure -> coords
// stay register-resident. Occupancy cap is free: only 4 blocks exist.
//
// Exactness contract (absmax must stay 0): d = (dx*dx+dy*dy)+dz*dz with
// contract(off) (no FMA), md = fminf(md, d), argmax tie-break = smallest
// original index (thread-local: strict >, ascending i; cross-lane: packed
// key (f32bits(val)<<32)|~idx max-reduced — min-dists >= 0 so f32 bits are
// monotone as u32; ~idx makes larger key == smaller index on value ties).
// ---------------------------------------------------------------------------

#define PT_FOREACH(X) \
  X(0) X(1) X(2) X(3) X(4) X(5) X(6) X(7) \
  X(8) X(9) X(10) X(11) X(12) X(13) X(14) X(15) \
  X(16) X(17) X(18) X(19) X(20) X(21) X(22) X(23) \
  X(24) X(25) X(26) X(27) X(28) X(29) X(30) X(31)

__global__ __launch_bounds__(FPS_TPB)
__attribute__((amdgpu_waves_per_eu(2, 2)))  // pin: allocator budget 256 VGPR
void fps_kernel(
    const float* __restrict__ xyz, float* __restrict__ centroids) {
#pragma clang fp contract(off)
  const int b = blockIdx.x;
  const int t = threadIdx.x;
  const float* px = xyz + (size_t)b * NPTS * 3;

#define DECL_PT(i) float x##i, y##i, z##i, m##i;
  PT_FOREACH(DECL_PT)
#undef DECL_PT

#define LOAD_PT(i)                              \
  {                                             \
    const int p = (i) * FPS_TPB + t;            \
    x##i = px[p * 3 + 0];                       \
    y##i = px[p * 3 + 1];                       \
    z##i = px[p * 3 + 2];                       \
    m##i = 1e10f;                               \
  }
  PT_FOREACH(LOAD_PT)
#undef LOAD_PT

  __shared__ unsigned long long s_wkey[2][FPS_TPB / 64];  // double-buffered

  float* co = centroids + (size_t)b * NSAMP * 3;

  // current "last centroid" coords, kept in registers across iterations
  float lx = px[0], ly = px[1], lz = px[2];
  if (t == 0) { co[0] = lx; co[1] = ly; co[2] = lz; }

  for (int s = 1; s < NSAMP; ++s) {
    float bv = -1.0f;
    int bj = 0;
#define UPD_PT(i)                                                   \
    {                                                               \
      const float dx = x##i - lx;                                   \
      const float dy = y##i - ly;                                   \
      const float dz = z##i - lz;                                   \
      const float d = (dx * dx + dy * dy) + dz * dz; /* no FMA */   \
      const float mm = fminf(m##i, d);                              \
      m##i = mm;                                                    \
      if (mm > bv) { bv = mm; bj = (i); }  /* strict >: min index */\
    }
    PT_FOREACH(UPD_PT)
#undef UPD_PT

    const unsigned int bi = (unsigned int)(bj * FPS_TPB + t);
    unsigned long long key =
        ((unsigned long long)__float_as_uint(bv) << 32) | (unsigned int)(~bi);

    // intra-wave butterfly max (6 steps over 64 lanes)
#pragma unroll
    for (int off = 1; off < 64; off <<= 1) {
      const unsigned long long ok = __shfl_xor(key, off);
      if (ok > key) key = ok;
    }
    if ((t & 63) == 0) s_wkey[s & 1][t >> 6] = key;
    __syncthreads();  // the ONLY barrier per iteration (LDS double-buffered)

    // replicated cross-wave reduce: all threads read the 8 wave winners
    // (same-address LDS reads broadcast, no conflicts)
    unsigned long long best = s_wkey[s & 1][0];
#pragma unroll
    for (int w = 1; w < FPS_TPB / 64; ++w) {
      const unsigned long long k2 = s_wkey[s & 1][w];
      if (k2 > best) best = k2;
    }
    const unsigned int widx = ~(unsigned int)best;

    // winner coords: all lanes load the same address -> one broadcast
    // vector transaction (L2-hot)
    lx = px[widx * 3 + 0];
    ly = px[widx * 3 + 1];
    lz = px[widx * 3 + 2];
    if (t == 0) {
      co[s * 3 + 0] = lx;
      co[s * 3 + 1] = ly;
      co[s * 3 + 2] = lz;
    }
  }
}

// ---------------------------------------------------------------------------
// Kernel 2: ball query (first K in-radius by index order, pad with first hit)
// + gather. One wave per (b,s) centroid; 4 waves per 256-thread block.
// Ordered chunk scan with ballot + prefix popcount, early exit at K found.
// (Validated bit-exact in round 0; unchanged.)
// ---------------------------------------------------------------------------
__global__ __launch_bounds__(256) void group_kernel(
    const float* __restrict__ xyz, const float* __restrict__ feat,
    const float* __restrict__ centroids,
    float* __restrict__ gxyz, float* __restrict__ gfeat) {
#pragma clang fp contract(off)
  const int wave = threadIdx.x >> 6;
  const int lane = threadIdx.x & 63;
  const int gw = blockIdx.x * 4 + wave;  // == b * NSAMP + s
  const int b = gw >> 10;

  const float* px = xyz + (size_t)b * NPTS * 3;
  const float* pc = centroids + (size_t)gw * 3;
  const float cx = pc[0], cy = pc[1], cz = pc[2];
  // float32(0.04): numpy compares f32 sqd against python-double 0.04 demoted
  // to f32. NOT 0.2f*0.2f (that's a different float, 1 ulp larger).
  const float rr = 0.04f;

  __shared__ int sh_idx[4][KNBR];
  __shared__ float sh_gx[4][KNBR * 3];

  int cnt = 0;
  for (int n0 = 0; n0 < NPTS && cnt < KNBR; n0 += 64) {
    const int p = n0 + lane;
    const float xx = px[p * 3 + 0];
    const float yy = px[p * 3 + 1];
    const float zz = px[p * 3 + 2];
    const float dx = xx - cx;
    const float dy = yy - cy;
    const float dz = zz - cz;
    const float d = (dx * dx + dy * dy) + dz * dz;  // contract(off): no FMA
    const bool in = d <= rr;
    const unsigned long long mask = __ballot(in);
    const int pos = cnt + (int)__popcll(mask & ((1ull << lane) - 1ull));
    if (in && pos < KNBR) {
      sh_idx[wave][pos] = p;
      sh_gx[wave][pos * 3 + 0] = dx;
      sh_gx[wave][pos * 3 + 1] = dy;
      sh_gx[wave][pos * 3 + 2] = dz;
    }
    cnt += (int)__popcll(mask);
  }
  // Safety: cannot happen (centroid is itself in-ball), but avoid garbage
  // indices if it somehow does.
  if (cnt == 0 && lane == 0) {
    sh_idx[wave][0] = 0;
    sh_gx[wave][0] = px[0] - cx;
    sh_gx[wave][1] = px[1] - cy;
    sh_gx[wave][2] = px[2] - cz;
  }
  const int nf0 = (cnt < 1) ? 1 : cnt;
  const int nf = (nf0 < KNBR) ? nf0 : KNBR;
  __syncthreads();
  // pad slots [nf, K) with the first hit (matches reference padding)
  if (lane < KNBR && lane >= nf) {
    sh_idx[wave][lane] = sh_idx[wave][0];
    sh_gx[wave][lane * 3 + 0] = sh_gx[wave][0];
    sh_gx[wave][lane * 3 + 1] = sh_gx[wave][1];
    sh_gx[wave][lane * 3 + 2] = sh_gx[wave][2];
  }
  __syncthreads();

  // write grouped_xyz: 96 floats per centroid
  float* ox = gxyz + (size_t)gw * KNBR * 3;
  const float* shf = sh_gx[wave];
  for (int j = lane; j < KNBR * 3; j += 64) ox[j] = shf[j];

  // gather features: K rows of 128 floats, float2 per lane (512 B/row)
  float* og = gfeat + (size_t)gw * KNBR * NCH;
  const float* pf = feat + (size_t)b * NPTS * NCH;
#pragma unroll 4
  for (int k = 0; k < KNBR; ++k) {
    const int row = sh_idx[wave][k];
    const float2 v = ((const float2*)(pf + (size_t)row * NCH))[lane];
    ((float2*)(og + (size_t)k * NCH))[lane] = v;
  }
}

extern "C" void kernel_launch(void* const* d_in, const int* in_sizes, int n_in,
                              void* d_out, int out_size, void* d_ws, size_t ws_size,
                              hipStream_t stream) {
  const float* xyz = (const float*)d_in[0];
  const float* feat = (const float*)d_in[1];
  float* out = (float*)d_out;
  const int B = in_sizes[0] / (NPTS * 3);

  float* centroids = out;                                   // [B,S,3]
  float* gxyz = centroids + (size_t)B * NSAMP * 3;          // [B,S,K,3]
  float* gfeat = gxyz + (size_t)B * NSAMP * KNBR * 3;       // [B,S,K,C]

  fps_kernel<<<B, FPS_TPB, 0, stream>>>(xyz, centroids);
  group_kernel<<<(B * NSAMP) / 4, 256, 0, stream>>>(xyz, feat, centroids, gxyz, gfeat);
}